// Round 11
// baseline (429.922 us; speedup 1.0000x reference)
//
#include <hip/hip_runtime.h>
#include <hip/hip_bf16.h>

typedef __attribute__((ext_vector_type(8))) short short8v;   // 8 bf16 (4 VGPR)
typedef __attribute__((ext_vector_type(4))) float f32x4;

#define PART 32  // pooled partial buffers (contention spreading)

static __device__ __forceinline__ unsigned short f2bf(float f) {
  __hip_bfloat16 b = __float2bfloat16(f);  // round-to-nearest-even
  return *reinterpret_cast<unsigned short*>(&b);
}
static __device__ __forceinline__ float bf2f(unsigned short u) {
  unsigned int x = ((unsigned int)u) << 16;
  return __builtin_bit_cast(float, x);
}
static __device__ __forceinline__ float bflo(unsigned int u) {
  return __builtin_bit_cast(float, u << 16);
}
static __device__ __forceinline__ float bfhi(unsigned int u) {
  return __builtin_bit_cast(float, u & 0xffff0000u);
}

// ---------------- in-degree histogram over dst ----------------------------
__global__ __launch_bounds__(256) void k_hist(const int* __restrict__ ei,
                                              int* __restrict__ cnt, int E) {
  int stride = gridDim.x * blockDim.x;
  for (int i = blockIdx.x * blockDim.x + threadIdx.x; i < E; i += stride)
    atomicAdd(&cnt[ei[E + i]], 1);
}

// ---------------- exclusive scan of cnt -> row_ptr ------------------------
__global__ __launch_bounds__(256) void k_scan1(const int* __restrict__ cnt,
                                               int* __restrict__ row_tmp,
                                               int* __restrict__ bsum, int N) {
  __shared__ int sd[256];
  const int tid = threadIdx.x;
  const int i = blockIdx.x * 256 + tid;
  int v = (i < N) ? cnt[i] : 0;
  sd[tid] = v;
  __syncthreads();
#pragma unroll
  for (int off = 1; off < 256; off <<= 1) {
    int t = (tid >= off) ? sd[tid - off] : 0;
    __syncthreads();
    sd[tid] += t;
    __syncthreads();
  }
  if (i < N) row_tmp[i] = sd[tid] - v;  // exclusive
  if (tid == 255) bsum[blockIdx.x] = sd[255];
}

__global__ __launch_bounds__(1024) void k_scan2(int* __restrict__ bsum, int nb) {
  __shared__ int sd[1024];
  const int t = threadIdx.x;
  int v = (t < nb) ? bsum[t] : 0;
  sd[t] = v;
  __syncthreads();
#pragma unroll
  for (int off = 1; off < 1024; off <<= 1) {
    int x = (t >= off) ? sd[t - off] : 0;
    __syncthreads();
    sd[t] += x;
    __syncthreads();
  }
  if (t < nb) bsum[t] = sd[t] - v;  // exclusive
}

// row_ptr + dis + graph boundaries + bucket cursors, one pass over N
__global__ __launch_bounds__(256) void k_scan3(const int* __restrict__ row_tmp,
                                               const int* __restrict__ bsum,
                                               const int* __restrict__ cnt,
                                               const int* __restrict__ batch,
                                               float* __restrict__ dis,
                                               int* __restrict__ row_ptr,
                                               int* __restrict__ bucket_cur,
                                               int* __restrict__ gstart, int N,
                                               int E) {
  const int i = blockIdx.x * 256 + threadIdx.x;
  if (i < N) {
    int rp = row_tmp[i] + bsum[i >> 8];
    row_ptr[i] = rp;
    if ((i & 255) == 0) bucket_cur[i >> 8] = rp;  // bucket = dst>>8
    dis[i] = 1.0f / sqrtf((float)cnt[i] + 1.0f);
    int b = batch[i];
    if (i == 0) {
      for (int g = 0; g <= b; ++g) gstart[g] = 0;
    } else {
      int p = batch[i - 1];
      for (int g = p + 1; g <= b; ++g) gstart[g] = i;
    }
    if (i == N - 1)
      for (int g = b + 1; g <= 8; ++g) gstart[g] = N;
  }
  if (i == 0) row_ptr[N] = E;
}

// ------- bucketize edges into dst>>8 regions as packed (s,d) pairs --------
__global__ __launch_bounds__(256) void k_b3(const int* __restrict__ ei,
                                            int* __restrict__ bucket_cur,
                                            uint2* __restrict__ pairs, int E) {
  __shared__ int cntD[512];
  __shared__ int gbase[512];
  const int t = threadIdx.x;
  for (int i = t; i < 512; i += 256) cntD[i] = 0;
  __syncthreads();
  const int base = blockIdx.x * 2048;
  int s[8], d[8], rk[8];
#pragma unroll
  for (int i = 0; i < 8; ++i) {
    int e = base + i * 256 + t;
    if (e < E) {
      s[i] = ei[e];
      d[i] = ei[E + e];
      rk[i] = atomicAdd(&cntD[d[i] >> 8], 1);
    }
  }
  __syncthreads();
  for (int i = t; i < 512; i += 256)
    if (cntD[i] > 0) gbase[i] = atomicAdd(&bucket_cur[i], cntD[i]);
  __syncthreads();
#pragma unroll
  for (int i = 0; i < 8; ++i) {
    int e = base + i * 256 + t;
    if (e < E)
      pairs[gbase[d[i] >> 8] + rk[i]] = make_uint2((unsigned)s[i], (unsigned)d[i]);
  }
}

// ------- per-bucket exact CSR fill: block-local col writes ----------------
__global__ __launch_bounds__(256) void k_b4(const int* __restrict__ row_ptr,
                                            const uint2* __restrict__ pairs,
                                            int* __restrict__ col, int N) {
  __shared__ int curL[257];
  const int n0 = blockIdx.x << 8;
  const int nn = min(256, N - n0);
  const int t = threadIdx.x;
  for (int i = t; i <= nn; i += 256) curL[i] = row_ptr[n0 + i];  // inclusive!
  __syncthreads();
  const int p0 = curL[0], p1 = curL[nn];
  __syncthreads();
  for (int idx = p0 + t; idx < p1; idx += 256) {
    uint2 pr = pairs[idx];
    int pos = atomicAdd(&curL[(int)pr.y - n0], 1);
    col[pos] = (int)pr.x;
  }
}

// ---------------- pack W (KxM fp32) into B-fragment layout ----------------
static __device__ __forceinline__ void pack_one(const float* __restrict__ W,
                                                unsigned short* __restrict__ Wp,
                                                int K, int M, int t) {
  int KT = K >> 5;
  int lane = t & 63;
  int tile = t >> 6;
  int kt = tile % KT;
  int ct = tile / KT;
  int c = ct * 16 + (lane & 15);
  int k0 = kt * 32 + (lane >> 4) * 8;
  unsigned short v[8];
#pragma unroll
  for (int j = 0; j < 8; ++j) v[j] = f2bf(W[(size_t)(k0 + j) * M + c]);
  ushort4* dst = (ushort4*)&Wp[(size_t)t * 8];
  dst[0] = make_ushort4(v[0], v[1], v[2], v[3]);
  dst[1] = make_ushort4(v[4], v[5], v[6], v[7]);
}

__global__ __launch_bounds__(256) void k_packall(
    const float* __restrict__ W1, const float* __restrict__ W2,
    const float* __restrict__ W3, unsigned short* __restrict__ Wp1,
    unsigned short* __restrict__ Wp2, unsigned short* __restrict__ Wp3) {
  int t = blockIdx.x * 256 + threadIdx.x;
  if (t < 1024)
    pack_one(W1, Wp1, 128, 64, t);          // 4*4*64 frags
  else if (t < 2048)
    pack_one(W2, Wp2, 64, 128, t - 1024);   // 8*2*64
  else if (t < 6144)
    pack_one(W3, Wp3, 128, 256, t - 2048);  // 16*4*64
}

// ------- CSR agg, M=64: wave/dst; 8 sub-waves x 8 lanes x 8ch (16B loads) -
template <bool EPI>
__global__ __launch_bounds__(256) void k_agg64(const int* __restrict__ row_ptr,
                                               const int* __restrict__ col,
                                               const float* __restrict__ dis,
                                               const unsigned short* __restrict__ Hin,
                                               const float* __restrict__ bias,
                                               unsigned short* __restrict__ Pout,
                                               int N) {
  const int lane = threadIdx.x & 63;
  int d = blockIdx.x * 4 + (threadIdx.x >> 6);
  if (d >= N) return;
  const int q = lane >> 3;   // sub-wave 0..7, one edge each
  const int cl = lane & 7;   // 8 lanes x 8ch = 64 channels
  const int cb = cl * 8;
  const float disd = dis[d];
  const int beg = row_ptr[d];
  const int end = row_ptr[d + 1];
  const int deg = end - beg;
  const int nedge = min(deg, 64);

  int s_l = d;
  float w_l = 0.f;
  if (lane < nedge) {
    s_l = col[beg + lane];
    w_l = dis[s_l] * disd;
  }

  float acc[8];
#pragma unroll
  for (int k = 0; k < 8; ++k) acc[k] = 0.f;
  if (q == 0) {  // self-loop on sub-wave 0
    uint4 u = *(const uint4*)&Hin[(size_t)d * 64 + cb];
    const float sc = disd * disd;
    acc[0] = bflo(u.x) * sc; acc[1] = bfhi(u.x) * sc;
    acc[2] = bflo(u.y) * sc; acc[3] = bfhi(u.y) * sc;
    acc[4] = bflo(u.z) * sc; acc[5] = bfhi(u.z) * sc;
    acc[6] = bflo(u.w) * sc; acc[7] = bfhi(u.w) * sc;
  }

  const int padded = (nedge + 15) & ~15;
  for (int base = 0; base < padded; base += 16) {
    int e0 = base + q, e1 = base + 8 + q;
    int s0 = __shfl(s_l, e0, 64);
    float w0 = __shfl(w_l, e0, 64);
    int s1 = __shfl(s_l, e1, 64);
    float w1 = __shfl(w_l, e1, 64);
    if (e0 >= nedge) { s0 = d; w0 = 0.f; }
    if (e1 >= nedge) { s1 = d; w1 = 0.f; }
    uint4 u0 = *(const uint4*)&Hin[(size_t)s0 * 64 + cb];
    uint4 u1 = *(const uint4*)&Hin[(size_t)s1 * 64 + cb];
    acc[0] = fmaf(bflo(u0.x), w0, acc[0]); acc[1] = fmaf(bfhi(u0.x), w0, acc[1]);
    acc[2] = fmaf(bflo(u0.y), w0, acc[2]); acc[3] = fmaf(bfhi(u0.y), w0, acc[3]);
    acc[4] = fmaf(bflo(u0.z), w0, acc[4]); acc[5] = fmaf(bfhi(u0.z), w0, acc[5]);
    acc[6] = fmaf(bflo(u0.w), w0, acc[6]); acc[7] = fmaf(bfhi(u0.w), w0, acc[7]);
    acc[0] = fmaf(bflo(u1.x), w1, acc[0]); acc[1] = fmaf(bfhi(u1.x), w1, acc[1]);
    acc[2] = fmaf(bflo(u1.y), w1, acc[2]); acc[3] = fmaf(bfhi(u1.y), w1, acc[3]);
    acc[4] = fmaf(bflo(u1.z), w1, acc[4]); acc[5] = fmaf(bfhi(u1.z), w1, acc[5]);
    acc[6] = fmaf(bflo(u1.w), w1, acc[6]); acc[7] = fmaf(bfhi(u1.w), w1, acc[7]);
  }
  if (deg > 64) {
    for (int j = beg + 64 + q; j < end; j += 8) {
      int s = col[j];
      float w = dis[s] * disd;
      uint4 u = *(const uint4*)&Hin[(size_t)s * 64 + cb];
      acc[0] = fmaf(bflo(u.x), w, acc[0]); acc[1] = fmaf(bfhi(u.x), w, acc[1]);
      acc[2] = fmaf(bflo(u.y), w, acc[2]); acc[3] = fmaf(bfhi(u.y), w, acc[3]);
      acc[4] = fmaf(bflo(u.z), w, acc[4]); acc[5] = fmaf(bfhi(u.z), w, acc[5]);
      acc[6] = fmaf(bflo(u.w), w, acc[6]); acc[7] = fmaf(bfhi(u.w), w, acc[7]);
    }
  }

#pragma unroll
  for (int k = 0; k < 8; ++k) {
    acc[k] += __shfl_xor(acc[k], 8, 64);
    acc[k] += __shfl_xor(acc[k], 16, 64);
    acc[k] += __shfl_xor(acc[k], 32, 64);
  }
  if (q == 0) {
    if (EPI) {
#pragma unroll
      for (int k = 0; k < 8; ++k) acc[k] = fmaxf(acc[k] + bias[cb + k], 0.f);
    }
    uint4 o;
    o.x = (unsigned)f2bf(acc[0]) | ((unsigned)f2bf(acc[1]) << 16);
    o.y = (unsigned)f2bf(acc[2]) | ((unsigned)f2bf(acc[3]) << 16);
    o.z = (unsigned)f2bf(acc[4]) | ((unsigned)f2bf(acc[5]) << 16);
    o.w = (unsigned)f2bf(acc[6]) | ((unsigned)f2bf(acc[7]) << 16);
    *(uint4*)&Pout[(size_t)d * 64 + cb] = o;
  }
}

// ------- CSR agg, M=128: wave/dst; 4 sub-waves x 16 lanes x 8ch -----------
__global__ __launch_bounds__(256) void k_agg128(const int* __restrict__ row_ptr,
                                                const int* __restrict__ col,
                                                const float* __restrict__ dis,
                                                const unsigned short* __restrict__ Hin,
                                                unsigned short* __restrict__ Pout,
                                                int N) {
  const int lane = threadIdx.x & 63;
  int d = blockIdx.x * 4 + (threadIdx.x >> 6);
  if (d >= N) return;
  const int q = lane >> 4;    // sub-wave 0..3
  const int cl = lane & 15;   // 16 lanes x 8ch = 128 channels
  const int cb = cl * 8;
  const float disd = dis[d];
  const int beg = row_ptr[d];
  const int end = row_ptr[d + 1];
  const int deg = end - beg;
  const int nedge = min(deg, 64);

  int s_l = d;
  float w_l = 0.f;
  if (lane < nedge) {
    s_l = col[beg + lane];
    w_l = dis[s_l] * disd;
  }

  float acc[8];
#pragma unroll
  for (int k = 0; k < 8; ++k) acc[k] = 0.f;
  if (q == 0) {  // self-loop
    uint4 u = *(const uint4*)&Hin[(size_t)d * 128 + cb];
    const float sc = disd * disd;
    acc[0] = bflo(u.x) * sc; acc[1] = bfhi(u.x) * sc;
    acc[2] = bflo(u.y) * sc; acc[3] = bfhi(u.y) * sc;
    acc[4] = bflo(u.z) * sc; acc[5] = bfhi(u.z) * sc;
    acc[6] = bflo(u.w) * sc; acc[7] = bfhi(u.w) * sc;
  }

  const int padded = (nedge + 7) & ~7;
  for (int base = 0; base < padded; base += 8) {
    int e0 = base + q, e1 = base + 4 + q;
    int s0 = __shfl(s_l, e0, 64);
    float w0 = __shfl(w_l, e0, 64);
    int s1 = __shfl(s_l, e1, 64);
    float w1 = __shfl(w_l, e1, 64);
    if (e0 >= nedge) { s0 = d; w0 = 0.f; }
    if (e1 >= nedge) { s1 = d; w1 = 0.f; }
    uint4 u0 = *(const uint4*)&Hin[(size_t)s0 * 128 + cb];
    uint4 u1 = *(const uint4*)&Hin[(size_t)s1 * 128 + cb];
    acc[0] = fmaf(bflo(u0.x), w0, acc[0]); acc[1] = fmaf(bfhi(u0.x), w0, acc[1]);
    acc[2] = fmaf(bflo(u0.y), w0, acc[2]); acc[3] = fmaf(bfhi(u0.y), w0, acc[3]);
    acc[4] = fmaf(bflo(u0.z), w0, acc[4]); acc[5] = fmaf(bfhi(u0.z), w0, acc[5]);
    acc[6] = fmaf(bflo(u0.w), w0, acc[6]); acc[7] = fmaf(bfhi(u0.w), w0, acc[7]);
    acc[0] = fmaf(bflo(u1.x), w1, acc[0]); acc[1] = fmaf(bfhi(u1.x), w1, acc[1]);
    acc[2] = fmaf(bflo(u1.y), w1, acc[2]); acc[3] = fmaf(bfhi(u1.y), w1, acc[3]);
    acc[4] = fmaf(bflo(u1.z), w1, acc[4]); acc[5] = fmaf(bfhi(u1.z), w1, acc[5]);
    acc[6] = fmaf(bflo(u1.w), w1, acc[6]); acc[7] = fmaf(bfhi(u1.w), w1, acc[7]);
  }
  if (deg > 64) {
    for (int j = beg + 64 + q; j < end; j += 4) {
      int s = col[j];
      float w = dis[s] * disd;
      uint4 u = *(const uint4*)&Hin[(size_t)s * 128 + cb];
      acc[0] = fmaf(bflo(u.x), w, acc[0]); acc[1] = fmaf(bfhi(u.x), w, acc[1]);
      acc[2] = fmaf(bflo(u.y), w, acc[2]); acc[3] = fmaf(bfhi(u.y), w, acc[3]);
      acc[4] = fmaf(bflo(u.z), w, acc[4]); acc[5] = fmaf(bfhi(u.z), w, acc[5]);
      acc[6] = fmaf(bflo(u.w), w, acc[6]); acc[7] = fmaf(bfhi(u.w), w, acc[7]);
    }
  }

#pragma unroll
  for (int k = 0; k < 8; ++k) {
    acc[k] += __shfl_xor(acc[k], 16, 64);
    acc[k] += __shfl_xor(acc[k], 32, 64);
  }
  if (q == 0) {
    uint4 o;
    o.x = (unsigned)f2bf(acc[0]) | ((unsigned)f2bf(acc[1]) << 16);
    o.y = (unsigned)f2bf(acc[2]) | ((unsigned)f2bf(acc[3]) << 16);
    o.z = (unsigned)f2bf(acc[4]) | ((unsigned)f2bf(acc[5]) << 16);
    o.w = (unsigned)f2bf(acc[6]) | ((unsigned)f2bf(acc[7]) << 16);
    *(uint4*)&Pout[(size_t)d * 128 + cb] = o;
  }
}

// ---------------- MFMA GEMM + LDS-coalesced store: Hout = [relu](A@W[+b]) -
template <int K, int M, bool F32IN, bool BIAS>
__global__ __launch_bounds__(256) void k_mm(const void* __restrict__ Ap,
                                            const unsigned short* __restrict__ Wp,
                                            const float* __restrict__ bias,
                                            unsigned short* __restrict__ Hout,
                                            int N) {
  constexpr int KT = K / 32, CT = M / 16;
  __shared__ unsigned short lds[64][M + 8];  // +8 pad: rows stay 16B-aligned
  const int lane = threadIdx.x & 63;
  const int wid = threadIdx.x >> 6;
  const int blk0 = blockIdx.x * 64;
  int row0 = blk0 + wid * 16;
  row0 = __builtin_amdgcn_readfirstlane(row0);
  const bool active = row0 < N;
  const int r = lane & 15;
  const int kh = lane >> 4;

  if (active) {
    int arow = row0 + r;
    if (arow >= N) arow = N - 1;

    f32x4 acc[CT];
#pragma unroll
    for (int ct = 0; ct < CT; ++ct) acc[ct] = (f32x4){0.f, 0.f, 0.f, 0.f};

#pragma unroll
    for (int kt = 0; kt < KT; ++kt) {
      short8v a;
      if (F32IN) {
        const float* Af = (const float*)Ap;
        const float* p = &Af[(size_t)arow * K + kt * 32 + kh * 8];
        float4 f0 = *(const float4*)p;
        float4 f1 = *(const float4*)(p + 4);
        a[0] = (short)f2bf(f0.x); a[1] = (short)f2bf(f0.y);
        a[2] = (short)f2bf(f0.z); a[3] = (short)f2bf(f0.w);
        a[4] = (short)f2bf(f1.x); a[5] = (short)f2bf(f1.y);
        a[6] = (short)f2bf(f1.z); a[7] = (short)f2bf(f1.w);
      } else {
        const unsigned short* Ab = (const unsigned short*)Ap;
        a = *(const short8v*)&Ab[(size_t)arow * K + kt * 32 + kh * 8];
      }
#pragma unroll
      for (int ct = 0; ct < CT; ++ct) {
        short8v b = *(const short8v*)&Wp[(size_t)((ct * KT + kt) * 64 + lane) * 8];
        acc[ct] = __builtin_amdgcn_mfma_f32_16x16x32_bf16(a, b, acc[ct], 0, 0, 0);
      }
    }

    const int lrow0 = wid * 16 + kh * 4;
#pragma unroll
    for (int ct = 0; ct < CT; ++ct) {
      const int c = ct * 16 + r;
      const float bv = BIAS ? bias[c] : 0.f;
#pragma unroll
      for (int reg = 0; reg < 4; ++reg) {
        float v = acc[ct][reg] + bv;
        if (BIAS) v = fmaxf(v, 0.f);
        lds[lrow0 + reg][c] = f2bf(v);
      }
    }
  }
  __syncthreads();
  // coalesced uint4 stores: 64 rows x M cols of bf16
  constexpr int CBK = M / 8;          // 16B chunks per row
  constexpr int ITER = 64 * CBK / 256;
  const int t = threadIdx.x;
#pragma unroll
  for (int it = 0; it < ITER; ++it) {
    int idx = it * 256 + t;
    int row = idx / CBK;
    int cbk = idx % CBK;
    if (blk0 + row < N)
      *(uint4*)&Hout[(size_t)(blk0 + row) * M + cbk * 8] =
          *(const uint4*)&lds[row][cbk * 8];
  }
}

// ------- MFMA GEMM L3 fused with pooling via LDS accumulation -------------
template <int K, int M>
__global__ __launch_bounds__(256) void k_mmpool(const unsigned short* __restrict__ Ab,
                                                const unsigned short* __restrict__ Wp,
                                                const float* __restrict__ bias,
                                                const int* __restrict__ batch,
                                                float* __restrict__ pooled_part,
                                                int N) {
  constexpr int KT = K / 32, CT = M / 16;
  __shared__ float ldsp[8][256];
  const int t = threadIdx.x;
  const int lane = t & 63;
  const int wid = t >> 6;
  const int blk0 = blockIdx.x * 64;
  int row0 = blk0 + wid * 16;
  row0 = __builtin_amdgcn_readfirstlane(row0);
  const bool active = row0 < N;
  const int r = lane & 15;
  const int kh = lane >> 4;

#pragma unroll
  for (int i = 0; i < 8; ++i) ldsp[i][t] = 0.f;
  __syncthreads();

  if (active) {
    int arow = row0 + r;
    if (arow >= N) arow = N - 1;

    f32x4 acc[CT];
#pragma unroll
    for (int ct = 0; ct < CT; ++ct) acc[ct] = (f32x4){0.f, 0.f, 0.f, 0.f};

#pragma unroll
    for (int kt = 0; kt < KT; ++kt) {
      short8v a = *(const short8v*)&Ab[(size_t)arow * K + kt * 32 + kh * 8];
#pragma unroll
      for (int ct = 0; ct < CT; ++ct) {
        short8v b = *(const short8v*)&Wp[(size_t)((ct * KT + kt) * 64 + lane) * 8];
        acc[ct] = __builtin_amdgcn_mfma_f32_16x16x32_bf16(a, b, acc[ct], 0, 0, 0);
      }
    }

    const int orow0 = row0 + kh * 4;
    int g[4];
#pragma unroll
    for (int reg = 0; reg < 4; ++reg) {
      int row = orow0 + reg;
      g[reg] = (row < N) ? batch[row] : 0;
    }
#pragma unroll
    for (int ct = 0; ct < CT; ++ct) {
      const int c = ct * 16 + r;
      const float bv = bias[c];
#pragma unroll
      for (int reg = 0; reg < 4; ++reg) {
        int row = orow0 + reg;
        float v = fmaxf(acc[ct][reg] + bv, 0.f);
        if (row < N && v != 0.f) atomicAdd(&ldsp[g[reg]][c], v);
      }
    }
  }
  __syncthreads();
  // one global atomic per (graph,col) with nonzero sum: ~256/block typical
  float* pp = pooled_part + (size_t)(blockIdx.x & (PART - 1)) * 2048;
#pragma unroll
  for (int gg = 0; gg < 8; ++gg) {
    float v = ldsp[gg][t];
    if (v != 0.f) atomicAdd(&pp[gg * 256 + t], v);
  }
}

// ---------------- final FC: out[g] = (sum partials)/cnt . Wfc + bfc -------
__global__ __launch_bounds__(256) void k_final(const float* __restrict__ pooled_part,
                                               const int* __restrict__ gstart,
                                               const float* __restrict__ Wfc,
                                               const float* __restrict__ bfc,
                                               float* __restrict__ out) {
  __shared__ float red[4];
  const int t = threadIdx.x;
  for (int g = 0; g < 8; ++g) {
    float v = 0.f;
    for (int p = 0; p < PART; ++p) v += pooled_part[p * 2048 + g * 256 + t];
    float cg = (float)(gstart[g + 1] - gstart[g]);
    v = v / cg * Wfc[t];
#pragma unroll
    for (int off = 32; off > 0; off >>= 1) v += __shfl_down(v, off, 64);
    if ((t & 63) == 0) red[t >> 6] = v;
    __syncthreads();
    if (t == 0) out[g] = red[0] + red[1] + red[2] + red[3] + bfc[0];
    __syncthreads();
  }
}

extern "C" void kernel_launch(void* const* d_in, const int* in_sizes, int n_in,
                              void* d_out, int out_size, void* d_ws,
                              size_t ws_size, hipStream_t stream) {
  const float* x = (const float*)d_in[0];
  const int* ei = (const int*)d_in[1];
  const int* batch = (const int*)d_in[2];
  const float* W1 = (const float*)d_in[3];
  const float* b1 = (const float*)d_in[4];
  const float* W2 = (const float*)d_in[5];
  const float* b2 = (const float*)d_in[6];
  const float* W3 = (const float*)d_in[7];
  const float* b3 = (const float*)d_in[8];
  const float* Wfc = (const float*)d_in[9];
  const float* bfc = (const float*)d_in[10];
  float* out = (float*)d_out;

  const int N = in_sizes[0] / 128;
  const int E = in_sizes[1] / 2;
  const int nb = (N + 255) / 256;
  const int nbk = (N + 255) >> 8;  // dst buckets (256 nodes each)

  // -------- workspace layout (4-byte units) --------
  float* ws = (float*)d_ws;
  size_t o = 0;
  float* dis = ws + o;            o += (size_t)N;
  int* cnt = (int*)(ws + o);      o += (size_t)N;
  int* row_tmp = (int*)(ws + o);  o += (size_t)N;
  int* bsum = (int*)(ws + o);     o += 1024;
  int* row_ptr = (int*)(ws + o);  o += (size_t)N + 1;
  int* bucket_cur = (int*)(ws + o); o += 512;
  int* col = (int*)(ws + o);      o += (size_t)E;
  uint2* pairs = (uint2*)(ws + o); o += (size_t)E * 2;
  float* pooled_part = ws + o;    o += (size_t)PART * 2048;
  int* gstart = (int*)(ws + o);   o += 16;
  unsigned short* Wp1 = (unsigned short*)(ws + o); o += 4096;   // 128x64 bf16
  unsigned short* Wp2 = (unsigned short*)(ws + o); o += 4096;   // 64x128
  unsigned short* Wp3 = (unsigned short*)(ws + o); o += 16384;  // 128x256
  o = (o + 63) & ~(size_t)63;
  unsigned short* bufA = (unsigned short*)(ws + o); o += (size_t)N * 32;  // t1 / P2 (64ch)
  unsigned short* bufB = (unsigned short*)(ws + o); o += (size_t)N * 32;  // h2 (64ch)
  unsigned short* bufC = (unsigned short*)(ws + o); o += (size_t)N * 64;  // h3 (128ch)
  unsigned short* bufD = (unsigned short*)(ws + o); o += (size_t)N * 64;  // P3 (128ch)

  hipMemsetAsync(cnt, 0, (size_t)N * sizeof(int), stream);
  hipMemsetAsync(pooled_part, 0, (size_t)PART * 2048 * sizeof(float), stream);

  k_hist<<<2048, 256, 0, stream>>>(ei, cnt, E);
  k_scan1<<<nb, 256, 0, stream>>>(cnt, row_tmp, bsum, N);
  k_scan2<<<1, 1024, 0, stream>>>(bsum, nb);
  k_scan3<<<nb, 256, 0, stream>>>(row_tmp, bsum, cnt, batch, dis, row_ptr,
                                  bucket_cur, gstart, N, E);
  k_b3<<<(E + 2047) / 2048, 256, 0, stream>>>(ei, bucket_cur, pairs, E);
  k_b4<<<nbk, 256, 0, stream>>>(row_ptr, pairs, col, N);
  k_packall<<<24, 256, 0, stream>>>(W1, W2, W3, Wp1, Wp2, Wp3);

  const int ablocks = (N + 3) / 4;
  const int mblocks = (N + 63) / 64;
  // L1: t1 = x @ W1 (fp32 in, raw out); h2 = relu(agg(t1) + b1)
  k_mm<128, 64, true, false><<<mblocks, 256, 0, stream>>>(x, Wp1, nullptr, bufA, N);
  k_agg64<true><<<ablocks, 256, 0, stream>>>(row_ptr, col, dis, bufA, b1, bufB, N);
  // L2: P2 = agg(h2); h3 = relu(P2 @ W2 + b2)
  k_agg64<false><<<ablocks, 256, 0, stream>>>(row_ptr, col, dis, bufB, nullptr, bufA, N);
  k_mm<64, 128, false, true><<<mblocks, 256, 0, stream>>>(bufA, Wp2, b2, bufC, N);
  // L3: P3 = agg(h3); pooled += relu(P3 @ W3 + b3)  (fused GEMM+pool, LDS acc)
  k_agg128<<<ablocks, 256, 0, stream>>>(row_ptr, col, dis, bufC, bufD, N);
  k_mmpool<128, 256><<<mblocks, 256, 0, stream>>>(bufD, Wp3, b3, batch,
                                                  pooled_part, N);

  k_final<<<1, 256, 0, stream>>>(pooled_part, gstart, Wfc, bfc, out);
}

// Round 12
// 385.522 us; speedup vs baseline: 1.1152x; 1.1152x over previous
//
#include <hip/hip_runtime.h>
#include <hip/hip_bf16.h>

typedef __attribute__((ext_vector_type(8))) short short8v;   // 8 bf16 (4 VGPR)
typedef __attribute__((ext_vector_type(4))) float f32x4;

static __device__ __forceinline__ unsigned short f2bf(float f) {
  __hip_bfloat16 b = __float2bfloat16(f);  // round-to-nearest-even
  return *reinterpret_cast<unsigned short*>(&b);
}
static __device__ __forceinline__ float bf2f(unsigned short u) {
  unsigned int x = ((unsigned int)u) << 16;
  return __builtin_bit_cast(float, x);
}
static __device__ __forceinline__ float bflo(unsigned int u) {
  return __builtin_bit_cast(float, u << 16);
}
static __device__ __forceinline__ float bfhi(unsigned int u) {
  return __builtin_bit_cast(float, u & 0xffff0000u);
}

// ---------------- in-degree histogram over dst ----------------------------
__global__ __launch_bounds__(256) void k_hist(const int* __restrict__ ei,
                                              int* __restrict__ cnt, int E) {
  int stride = gridDim.x * blockDim.x;
  for (int i = blockIdx.x * blockDim.x + threadIdx.x; i < E; i += stride)
    atomicAdd(&cnt[ei[E + i]], 1);
}

// ---------------- exclusive scan of cnt -> row_ptr ------------------------
__global__ __launch_bounds__(256) void k_scan1(const int* __restrict__ cnt,
                                               int* __restrict__ row_tmp,
                                               int* __restrict__ bsum, int N) {
  __shared__ int sd[256];
  const int tid = threadIdx.x;
  const int i = blockIdx.x * 256 + tid;
  int v = (i < N) ? cnt[i] : 0;
  sd[tid] = v;
  __syncthreads();
#pragma unroll
  for (int off = 1; off < 256; off <<= 1) {
    int t = (tid >= off) ? sd[tid - off] : 0;
    __syncthreads();
    sd[tid] += t;
    __syncthreads();
  }
  if (i < N) row_tmp[i] = sd[tid] - v;  // exclusive
  if (tid == 255) bsum[blockIdx.x] = sd[255];
}

__global__ __launch_bounds__(1024) void k_scan2(int* __restrict__ bsum, int nb) {
  __shared__ int sd[1024];
  const int t = threadIdx.x;
  int v = (t < nb) ? bsum[t] : 0;
  sd[t] = v;
  __syncthreads();
#pragma unroll
  for (int off = 1; off < 1024; off <<= 1) {
    int x = (t >= off) ? sd[t - off] : 0;
    __syncthreads();
    sd[t] += x;
    __syncthreads();
  }
  if (t < nb) bsum[t] = sd[t] - v;  // exclusive
}

// row_ptr + dis + graph boundaries + bucket cursors, one pass over N
__global__ __launch_bounds__(256) void k_scan3(const int* __restrict__ row_tmp,
                                               const int* __restrict__ bsum,
                                               const int* __restrict__ cnt,
                                               const int* __restrict__ batch,
                                               float* __restrict__ dis,
                                               int* __restrict__ row_ptr,
                                               int* __restrict__ bucket_cur,
                                               int* __restrict__ gstart, int N,
                                               int E) {
  const int i = blockIdx.x * 256 + threadIdx.x;
  if (i < N) {
    int rp = row_tmp[i] + bsum[i >> 8];
    row_ptr[i] = rp;
    if ((i & 255) == 0) bucket_cur[i >> 8] = rp;  // bucket = dst>>8
    dis[i] = 1.0f / sqrtf((float)cnt[i] + 1.0f);
    int b = batch[i];
    if (i == 0) {
      for (int g = 0; g <= b; ++g) gstart[g] = 0;
    } else {
      int p = batch[i - 1];
      for (int g = p + 1; g <= b; ++g) gstart[g] = i;
    }
    if (i == N - 1)
      for (int g = b + 1; g <= 8; ++g) gstart[g] = N;
  }
  if (i == 0) row_ptr[N] = E;
}

// ------- bucketize edges into dst>>8 regions as packed (s,d) pairs --------
__global__ __launch_bounds__(256) void k_b3(const int* __restrict__ ei,
                                            int* __restrict__ bucket_cur,
                                            uint2* __restrict__ pairs, int E) {
  __shared__ int cntD[512];
  __shared__ int gbase[512];
  const int t = threadIdx.x;
  for (int i = t; i < 512; i += 256) cntD[i] = 0;
  __syncthreads();
  const int base = blockIdx.x * 2048;
  int s[8], d[8], rk[8];
#pragma unroll
  for (int i = 0; i < 8; ++i) {
    int e = base + i * 256 + t;
    if (e < E) {
      s[i] = ei[e];
      d[i] = ei[E + e];
      rk[i] = atomicAdd(&cntD[d[i] >> 8], 1);
    }
  }
  __syncthreads();
  for (int i = t; i < 512; i += 256)
    if (cntD[i] > 0) gbase[i] = atomicAdd(&bucket_cur[i], cntD[i]);
  __syncthreads();
#pragma unroll
  for (int i = 0; i < 8; ++i) {
    int e = base + i * 256 + t;
    if (e < E)
      pairs[gbase[d[i] >> 8] + rk[i]] = make_uint2((unsigned)s[i], (unsigned)d[i]);
  }
}

// ------- per-bucket exact CSR fill: block-local col writes ----------------
__global__ __launch_bounds__(256) void k_b4(const int* __restrict__ row_ptr,
                                            const uint2* __restrict__ pairs,
                                            int* __restrict__ col, int N) {
  __shared__ int curL[257];
  const int n0 = blockIdx.x << 8;
  const int nn = min(256, N - n0);
  const int t = threadIdx.x;
  for (int i = t; i <= nn; i += 256) curL[i] = row_ptr[n0 + i];  // inclusive!
  __syncthreads();
  const int p0 = curL[0], p1 = curL[nn];
  __syncthreads();
  for (int idx = p0 + t; idx < p1; idx += 256) {
    uint2 pr = pairs[idx];
    int pos = atomicAdd(&curL[(int)pr.y - n0], 1);
    col[pos] = (int)pr.x;
  }
}

// ---------------- pack W (KxM fp32) into B-fragment layout ----------------
static __device__ __forceinline__ void pack_one(const float* __restrict__ W,
                                                unsigned short* __restrict__ Wp,
                                                int K, int M, int t) {
  int KT = K >> 5;
  int lane = t & 63;
  int tile = t >> 6;
  int kt = tile % KT;
  int ct = tile / KT;
  int c = ct * 16 + (lane & 15);
  int k0 = kt * 32 + (lane >> 4) * 8;
  unsigned short v[8];
#pragma unroll
  for (int j = 0; j < 8; ++j) v[j] = f2bf(W[(size_t)(k0 + j) * M + c]);
  ushort4* dst = (ushort4*)&Wp[(size_t)t * 8];
  dst[0] = make_ushort4(v[0], v[1], v[2], v[3]);
  dst[1] = make_ushort4(v[4], v[5], v[6], v[7]);
}

__global__ __launch_bounds__(256) void k_packall(
    const float* __restrict__ W1, const float* __restrict__ W2,
    const float* __restrict__ W3, unsigned short* __restrict__ Wp1,
    unsigned short* __restrict__ Wp2, unsigned short* __restrict__ Wp3) {
  int t = blockIdx.x * 256 + threadIdx.x;
  if (t < 1024)
    pack_one(W1, Wp1, 128, 64, t);          // 4*4*64 frags
  else if (t < 2048)
    pack_one(W2, Wp2, 64, 128, t - 1024);   // 8*2*64
  else if (t < 6144)
    pack_one(W3, Wp3, 128, 256, t - 2048);  // 16*4*64
}

// ------- CSR agg, M=64: wave/dst; 8 sub-waves x 8 lanes x 8ch (16B loads) -
template <bool EPI>
__global__ __launch_bounds__(256) void k_agg64(const int* __restrict__ row_ptr,
                                               const int* __restrict__ col,
                                               const float* __restrict__ dis,
                                               const unsigned short* __restrict__ Hin,
                                               const float* __restrict__ bias,
                                               unsigned short* __restrict__ Pout,
                                               int N) {
  const int lane = threadIdx.x & 63;
  int d = blockIdx.x * 4 + (threadIdx.x >> 6);
  if (d >= N) return;
  const int q = lane >> 3;   // sub-wave 0..7, one edge each
  const int cl = lane & 7;   // 8 lanes x 8ch = 64 channels
  const int cb = cl * 8;
  const float disd = dis[d];
  const int beg = row_ptr[d];
  const int end = row_ptr[d + 1];
  const int deg = end - beg;
  const int nedge = min(deg, 64);

  int s_l = d;
  float w_l = 0.f;
  if (lane < nedge) {
    s_l = col[beg + lane];
    w_l = dis[s_l] * disd;
  }

  float acc[8];
#pragma unroll
  for (int k = 0; k < 8; ++k) acc[k] = 0.f;
  if (q == 0) {  // self-loop on sub-wave 0
    uint4 u = *(const uint4*)&Hin[(size_t)d * 64 + cb];
    const float sc = disd * disd;
    acc[0] = bflo(u.x) * sc; acc[1] = bfhi(u.x) * sc;
    acc[2] = bflo(u.y) * sc; acc[3] = bfhi(u.y) * sc;
    acc[4] = bflo(u.z) * sc; acc[5] = bfhi(u.z) * sc;
    acc[6] = bflo(u.w) * sc; acc[7] = bfhi(u.w) * sc;
  }

  const int padded = (nedge + 15) & ~15;
  for (int base = 0; base < padded; base += 16) {
    int e0 = base + q, e1 = base + 8 + q;
    int s0 = __shfl(s_l, e0, 64);
    float w0 = __shfl(w_l, e0, 64);
    int s1 = __shfl(s_l, e1, 64);
    float w1 = __shfl(w_l, e1, 64);
    if (e0 >= nedge) { s0 = d; w0 = 0.f; }
    if (e1 >= nedge) { s1 = d; w1 = 0.f; }
    uint4 u0 = *(const uint4*)&Hin[(size_t)s0 * 64 + cb];
    uint4 u1 = *(const uint4*)&Hin[(size_t)s1 * 64 + cb];
    acc[0] = fmaf(bflo(u0.x), w0, acc[0]); acc[1] = fmaf(bfhi(u0.x), w0, acc[1]);
    acc[2] = fmaf(bflo(u0.y), w0, acc[2]); acc[3] = fmaf(bfhi(u0.y), w0, acc[3]);
    acc[4] = fmaf(bflo(u0.z), w0, acc[4]); acc[5] = fmaf(bfhi(u0.z), w0, acc[5]);
    acc[6] = fmaf(bflo(u0.w), w0, acc[6]); acc[7] = fmaf(bfhi(u0.w), w0, acc[7]);
    acc[0] = fmaf(bflo(u1.x), w1, acc[0]); acc[1] = fmaf(bfhi(u1.x), w1, acc[1]);
    acc[2] = fmaf(bflo(u1.y), w1, acc[2]); acc[3] = fmaf(bfhi(u1.y), w1, acc[3]);
    acc[4] = fmaf(bflo(u1.z), w1, acc[4]); acc[5] = fmaf(bfhi(u1.z), w1, acc[5]);
    acc[6] = fmaf(bflo(u1.w), w1, acc[6]); acc[7] = fmaf(bfhi(u1.w), w1, acc[7]);
  }
  if (deg > 64) {
    for (int j = beg + 64 + q; j < end; j += 8) {
      int s = col[j];
      float w = dis[s] * disd;
      uint4 u = *(const uint4*)&Hin[(size_t)s * 64 + cb];
      acc[0] = fmaf(bflo(u.x), w, acc[0]); acc[1] = fmaf(bfhi(u.x), w, acc[1]);
      acc[2] = fmaf(bflo(u.y), w, acc[2]); acc[3] = fmaf(bfhi(u.y), w, acc[3]);
      acc[4] = fmaf(bflo(u.z), w, acc[4]); acc[5] = fmaf(bfhi(u.z), w, acc[5]);
      acc[6] = fmaf(bflo(u.w), w, acc[6]); acc[7] = fmaf(bfhi(u.w), w, acc[7]);
    }
  }

#pragma unroll
  for (int k = 0; k < 8; ++k) {
    acc[k] += __shfl_xor(acc[k], 8, 64);
    acc[k] += __shfl_xor(acc[k], 16, 64);
    acc[k] += __shfl_xor(acc[k], 32, 64);
  }
  if (q == 0) {
    if (EPI) {
#pragma unroll
      for (int k = 0; k < 8; ++k) acc[k] = fmaxf(acc[k] + bias[cb + k], 0.f);
    }
    uint4 o;
    o.x = (unsigned)f2bf(acc[0]) | ((unsigned)f2bf(acc[1]) << 16);
    o.y = (unsigned)f2bf(acc[2]) | ((unsigned)f2bf(acc[3]) << 16);
    o.z = (unsigned)f2bf(acc[4]) | ((unsigned)f2bf(acc[5]) << 16);
    o.w = (unsigned)f2bf(acc[6]) | ((unsigned)f2bf(acc[7]) << 16);
    *(uint4*)&Pout[(size_t)d * 64 + cb] = o;
  }
}

// ------- CSR agg, M=128: wave/dst; 4 sub-waves x 16 lanes x 8ch -----------
__global__ __launch_bounds__(256) void k_agg128(const int* __restrict__ row_ptr,
                                                const int* __restrict__ col,
                                                const float* __restrict__ dis,
                                                const unsigned short* __restrict__ Hin,
                                                unsigned short* __restrict__ Pout,
                                                int N) {
  const int lane = threadIdx.x & 63;
  int d = blockIdx.x * 4 + (threadIdx.x >> 6);
  if (d >= N) return;
  const int q = lane >> 4;    // sub-wave 0..3
  const int cl = lane & 15;   // 16 lanes x 8ch = 128 channels
  const int cb = cl * 8;
  const float disd = dis[d];
  const int beg = row_ptr[d];
  const int end = row_ptr[d + 1];
  const int deg = end - beg;
  const int nedge = min(deg, 64);

  int s_l = d;
  float w_l = 0.f;
  if (lane < nedge) {
    s_l = col[beg + lane];
    w_l = dis[s_l] * disd;
  }

  float acc[8];
#pragma unroll
  for (int k = 0; k < 8; ++k) acc[k] = 0.f;
  if (q == 0) {  // self-loop
    uint4 u = *(const uint4*)&Hin[(size_t)d * 128 + cb];
    const float sc = disd * disd;
    acc[0] = bflo(u.x) * sc; acc[1] = bfhi(u.x) * sc;
    acc[2] = bflo(u.y) * sc; acc[3] = bfhi(u.y) * sc;
    acc[4] = bflo(u.z) * sc; acc[5] = bfhi(u.z) * sc;
    acc[6] = bflo(u.w) * sc; acc[7] = bfhi(u.w) * sc;
  }

  const int padded = (nedge + 7) & ~7;
  for (int base = 0; base < padded; base += 8) {
    int e0 = base + q, e1 = base + 4 + q;
    int s0 = __shfl(s_l, e0, 64);
    float w0 = __shfl(w_l, e0, 64);
    int s1 = __shfl(s_l, e1, 64);
    float w1 = __shfl(w_l, e1, 64);
    if (e0 >= nedge) { s0 = d; w0 = 0.f; }
    if (e1 >= nedge) { s1 = d; w1 = 0.f; }
    uint4 u0 = *(const uint4*)&Hin[(size_t)s0 * 128 + cb];
    uint4 u1 = *(const uint4*)&Hin[(size_t)s1 * 128 + cb];
    acc[0] = fmaf(bflo(u0.x), w0, acc[0]); acc[1] = fmaf(bfhi(u0.x), w0, acc[1]);
    acc[2] = fmaf(bflo(u0.y), w0, acc[2]); acc[3] = fmaf(bfhi(u0.y), w0, acc[3]);
    acc[4] = fmaf(bflo(u0.z), w0, acc[4]); acc[5] = fmaf(bfhi(u0.z), w0, acc[5]);
    acc[6] = fmaf(bflo(u0.w), w0, acc[6]); acc[7] = fmaf(bfhi(u0.w), w0, acc[7]);
    acc[0] = fmaf(bflo(u1.x), w1, acc[0]); acc[1] = fmaf(bfhi(u1.x), w1, acc[1]);
    acc[2] = fmaf(bflo(u1.y), w1, acc[2]); acc[3] = fmaf(bfhi(u1.y), w1, acc[3]);
    acc[4] = fmaf(bflo(u1.z), w1, acc[4]); acc[5] = fmaf(bfhi(u1.z), w1, acc[5]);
    acc[6] = fmaf(bflo(u1.w), w1, acc[6]); acc[7] = fmaf(bfhi(u1.w), w1, acc[7]);
  }
  if (deg > 64) {
    for (int j = beg + 64 + q; j < end; j += 4) {
      int s = col[j];
      float w = dis[s] * disd;
      uint4 u = *(const uint4*)&Hin[(size_t)s * 128 + cb];
      acc[0] = fmaf(bflo(u.x), w, acc[0]); acc[1] = fmaf(bfhi(u.x), w, acc[1]);
      acc[2] = fmaf(bflo(u.y), w, acc[2]); acc[3] = fmaf(bfhi(u.y), w, acc[3]);
      acc[4] = fmaf(bflo(u.z), w, acc[4]); acc[5] = fmaf(bfhi(u.z), w, acc[5]);
      acc[6] = fmaf(bflo(u.w), w, acc[6]); acc[7] = fmaf(bfhi(u.w), w, acc[7]);
    }
  }

#pragma unroll
  for (int k = 0; k < 8; ++k) {
    acc[k] += __shfl_xor(acc[k], 16, 64);
    acc[k] += __shfl_xor(acc[k], 32, 64);
  }
  if (q == 0) {
    uint4 o;
    o.x = (unsigned)f2bf(acc[0]) | ((unsigned)f2bf(acc[1]) << 16);
    o.y = (unsigned)f2bf(acc[2]) | ((unsigned)f2bf(acc[3]) << 16);
    o.z = (unsigned)f2bf(acc[4]) | ((unsigned)f2bf(acc[5]) << 16);
    o.w = (unsigned)f2bf(acc[6]) | ((unsigned)f2bf(acc[7]) << 16);
    *(uint4*)&Pout[(size_t)d * 128 + cb] = o;
  }
}

// ------- MFMA GEMM, column-split waves: block=64 rows, wave w owns CT/4 ---
// cols. B fragments read once per 64 rows (4x reuse vs 16-row waves).
// A frag: lane holds A[rt*16+(lane&15)][kt*32+(lane>>4)*8+0..7]
// D frag: row=(lane>>4)*4+reg, col=lane&15
template <int K, int M, bool F32IN, bool BIAS>
__global__ __launch_bounds__(256) void k_mmx(const void* __restrict__ Ap,
                                             const unsigned short* __restrict__ Wp,
                                             const float* __restrict__ bias,
                                             unsigned short* __restrict__ Hout,
                                             int N) {
  constexpr int KT = K / 32, CTW = M / 64;  // col-tiles per wave
  __shared__ unsigned short lds[64][M + 8];  // rows 16B-aligned (M+8 even*8)
  const int lane = threadIdx.x & 63;
  const int wid = threadIdx.x >> 6;
  const int blk0 = blockIdx.x * 64;
  const int r = lane & 15;
  const int kh = lane >> 4;

  int ar[4];
#pragma unroll
  for (int rt = 0; rt < 4; ++rt) ar[rt] = min(blk0 + rt * 16 + r, N - 1);

  f32x4 acc[4][CTW];
#pragma unroll
  for (int rt = 0; rt < 4; ++rt)
#pragma unroll
    for (int c = 0; c < CTW; ++c) acc[rt][c] = (f32x4){0.f, 0.f, 0.f, 0.f};

#pragma unroll
  for (int kt = 0; kt < KT; ++kt) {
    short8v a[4];
#pragma unroll
    for (int rt = 0; rt < 4; ++rt) {
      if (F32IN) {
        const float* Af = (const float*)Ap;
        const float* p = &Af[(size_t)ar[rt] * K + kt * 32 + kh * 8];
        float4 f0 = *(const float4*)p;
        float4 f1 = *(const float4*)(p + 4);
        a[rt][0] = (short)f2bf(f0.x); a[rt][1] = (short)f2bf(f0.y);
        a[rt][2] = (short)f2bf(f0.z); a[rt][3] = (short)f2bf(f0.w);
        a[rt][4] = (short)f2bf(f1.x); a[rt][5] = (short)f2bf(f1.y);
        a[rt][6] = (short)f2bf(f1.z); a[rt][7] = (short)f2bf(f1.w);
      } else {
        const unsigned short* Ab = (const unsigned short*)Ap;
        a[rt] = *(const short8v*)&Ab[(size_t)ar[rt] * K + kt * 32 + kh * 8];
      }
    }
#pragma unroll
    for (int c = 0; c < CTW; ++c) {
      const int ct = wid * CTW + c;
      short8v b = *(const short8v*)&Wp[(size_t)((ct * KT + kt) * 64 + lane) * 8];
#pragma unroll
      for (int rt = 0; rt < 4; ++rt)
        acc[rt][c] = __builtin_amdgcn_mfma_f32_16x16x32_bf16(a[rt], b, acc[rt][c], 0, 0, 0);
    }
  }

#pragma unroll
  for (int c = 0; c < CTW; ++c) {
    const int col = (wid * CTW + c) * 16 + r;
    const float bv = BIAS ? bias[col] : 0.f;
#pragma unroll
    for (int rt = 0; rt < 4; ++rt) {
      const int lrow0 = rt * 16 + kh * 4;
#pragma unroll
      for (int reg = 0; reg < 4; ++reg) {
        float v = acc[rt][c][reg] + bv;
        if (BIAS) v = fmaxf(v, 0.f);
        lds[lrow0 + reg][col] = f2bf(v);
      }
    }
  }
  __syncthreads();
  // coalesced uint4 stores: 64 rows x M cols of bf16
  constexpr int CBK = M / 8;          // 16B chunks per row
  constexpr int ITER = 64 * CBK / 256;
  const int t = threadIdx.x;
#pragma unroll
  for (int it = 0; it < ITER; ++it) {
    int idx = it * 256 + t;
    int row = idx / CBK;
    int cbk = idx % CBK;
    if (blk0 + row < N)
      *(uint4*)&Hout[(size_t)(blk0 + row) * M + cbk * 8] =
          *(const uint4*)&lds[row][cbk * 8];
  }
}

// ---------------- pooling: per-graph segmented sum over sorted rows -------
__global__ __launch_bounds__(256) void k_pool2(const unsigned short* __restrict__ H4,
                                               const int* __restrict__ gstart,
                                               float* __restrict__ pooled) {
  __shared__ float sd[8][256];
  const int g = blockIdx.y;
  const int s = gstart[g], e = gstart[g + 1];
  if (s >= e) return;  // uniform per block
  const int PB = gridDim.x;
  const int chunk = (e - s + PB - 1) / PB;
  const int r0 = s + blockIdx.x * chunk;
  const int r1 = min(e, r0 + chunk);

  const int t = threadIdx.x;
  const int rs = t >> 5;
  const int cl = t & 31;
  const int cb = cl * 8;

  float a[8];
#pragma unroll
  for (int k = 0; k < 8; ++k) a[k] = 0.f;

  for (int r = r0 + rs; r < r1; r += 8) {
    uint4 u = *(const uint4*)&H4[(size_t)r * 256 + cb];
    a[0] += bflo(u.x); a[1] += bfhi(u.x);
    a[2] += bflo(u.y); a[3] += bfhi(u.y);
    a[4] += bflo(u.z); a[5] += bfhi(u.z);
    a[6] += bflo(u.w); a[7] += bfhi(u.w);
  }
#pragma unroll
  for (int k = 0; k < 8; ++k) sd[rs][cb + k] = a[k];
  __syncthreads();
  float v = 0.f;
#pragma unroll
  for (int q = 0; q < 8; ++q) v += sd[q][t];
  atomicAdd(&pooled[g * 256 + t], v);
}

// ---------------- final FC: out[g] = pooled[g]/cnt . Wfc + bfc ------------
__global__ __launch_bounds__(256) void k_final(const float* __restrict__ pooled,
                                               const int* __restrict__ gstart,
                                               const float* __restrict__ Wfc,
                                               const float* __restrict__ bfc,
                                               float* __restrict__ out) {
  __shared__ float red[4];
  const int t = threadIdx.x;
  for (int g = 0; g < 8; ++g) {
    float cg = (float)(gstart[g + 1] - gstart[g]);
    float v = pooled[g * 256 + t] / cg * Wfc[t];
#pragma unroll
    for (int off = 32; off > 0; off >>= 1) v += __shfl_down(v, off, 64);
    if ((t & 63) == 0) red[t >> 6] = v;
    __syncthreads();
    if (t == 0) out[g] = red[0] + red[1] + red[2] + red[3] + bfc[0];
    __syncthreads();
  }
}

extern "C" void kernel_launch(void* const* d_in, const int* in_sizes, int n_in,
                              void* d_out, int out_size, void* d_ws,
                              size_t ws_size, hipStream_t stream) {
  const float* x = (const float*)d_in[0];
  const int* ei = (const int*)d_in[1];
  const int* batch = (const int*)d_in[2];
  const float* W1 = (const float*)d_in[3];
  const float* b1 = (const float*)d_in[4];
  const float* W2 = (const float*)d_in[5];
  const float* b2 = (const float*)d_in[6];
  const float* W3 = (const float*)d_in[7];
  const float* b3 = (const float*)d_in[8];
  const float* Wfc = (const float*)d_in[9];
  const float* bfc = (const float*)d_in[10];
  float* out = (float*)d_out;

  const int N = in_sizes[0] / 128;
  const int E = in_sizes[1] / 2;
  const int nb = (N + 255) / 256;
  const int nbk = (N + 255) >> 8;  // dst buckets (256 nodes each)

  // -------- workspace layout (4-byte units) --------
  float* ws = (float*)d_ws;
  size_t o = 0;
  float* dis = ws + o;            o += (size_t)N;
  int* cnt = (int*)(ws + o);      o += (size_t)N;
  int* row_tmp = (int*)(ws + o);  o += (size_t)N;
  int* bsum = (int*)(ws + o);     o += 1024;
  int* row_ptr = (int*)(ws + o);  o += (size_t)N + 1;
  int* bucket_cur = (int*)(ws + o); o += 512;
  int* col = (int*)(ws + o);      o += (size_t)E;
  uint2* pairs = (uint2*)(ws + o); o += (size_t)E * 2;
  float* pooled = ws + o;         o += 2048;
  int* gstart = (int*)(ws + o);   o += 16;
  unsigned short* Wp1 = (unsigned short*)(ws + o); o += 4096;   // 128x64 bf16
  unsigned short* Wp2 = (unsigned short*)(ws + o); o += 4096;   // 64x128
  unsigned short* Wp3 = (unsigned short*)(ws + o); o += 16384;  // 128x256
  o = (o + 63) & ~(size_t)63;
  unsigned short* bufA = (unsigned short*)(ws + o); o += (size_t)N * 32;  // t1 / P2 (64ch)
  unsigned short* bufB = (unsigned short*)(ws + o); o += (size_t)N * 32;  // h2 (64ch)
  unsigned short* bufC = (unsigned short*)(ws + o); o += (size_t)N * 64;  // h3 (128ch)
  unsigned short* bufD = (unsigned short*)(ws + o); o += (size_t)N * 64;  // P3 (128ch)
  unsigned short* bufE = (unsigned short*)(ws + o); o += (size_t)N * 128; // h4 (256ch)

  hipMemsetAsync(cnt, 0, (size_t)N * sizeof(int), stream);
  hipMemsetAsync(pooled, 0, 2048 * sizeof(float), stream);

  k_hist<<<2048, 256, 0, stream>>>(ei, cnt, E);
  k_scan1<<<nb, 256, 0, stream>>>(cnt, row_tmp, bsum, N);
  k_scan2<<<1, 1024, 0, stream>>>(bsum, nb);
  k_scan3<<<nb, 256, 0, stream>>>(row_tmp, bsum, cnt, batch, dis, row_ptr,
                                  bucket_cur, gstart, N, E);
  k_b3<<<(E + 2047) / 2048, 256, 0, stream>>>(ei, bucket_cur, pairs, E);
  k_b4<<<nbk, 256, 0, stream>>>(row_ptr, pairs, col, N);
  k_packall<<<24, 256, 0, stream>>>(W1, W2, W3, Wp1, Wp2, Wp3);

  const int ablocks = (N + 3) / 4;
  const int mblocks = (N + 63) / 64;
  // L1: t1 = x @ W1 (fp32 in, raw out); h2 = relu(agg(t1) + b1)
  k_mmx<128, 64, true, false><<<mblocks, 256, 0, stream>>>(x, Wp1, nullptr, bufA, N);
  k_agg64<true><<<ablocks, 256, 0, stream>>>(row_ptr, col, dis, bufA, b1, bufB, N);
  // L2: P2 = agg(h2); h3 = relu(P2 @ W2 + b2)
  k_agg64<false><<<ablocks, 256, 0, stream>>>(row_ptr, col, dis, bufB, nullptr, bufA, N);
  k_mmx<64, 128, false, true><<<mblocks, 256, 0, stream>>>(bufA, Wp2, b2, bufC, N);
  // L3: P3 = agg(h3); h4 = relu(P3 @ W3 + b3)
  k_agg128<<<ablocks, 256, 0, stream>>>(row_ptr, col, dis, bufC, bufD, N);
  k_mmx<128, 256, false, true><<<mblocks, 256, 0, stream>>>(bufD, Wp3, b3, bufE, N);

  k_pool2<<<dim3(128, 8), 256, 0, stream>>>(bufE, gstart, pooled);
  k_final<<<1, 256, 0, stream>>>(pooled, gstart, Wfc, bfc, out);
}

// Round 13
// 362.834 us; speedup vs baseline: 1.1849x; 1.0625x over previous
//
#include <hip/hip_runtime.h>
#include <hip/hip_bf16.h>

typedef __attribute__((ext_vector_type(8))) short short8v;   // 8 bf16 (4 VGPR)
typedef __attribute__((ext_vector_type(4))) float f32x4;

static __device__ __forceinline__ unsigned short f2bf(float f) {
  __hip_bfloat16 b = __float2bfloat16(f);  // round-to-nearest-even
  return *reinterpret_cast<unsigned short*>(&b);
}
static __device__ __forceinline__ float bf2f(unsigned short u) {
  unsigned int x = ((unsigned int)u) << 16;
  return __builtin_bit_cast(float, x);
}
static __device__ __forceinline__ float bflo(unsigned int u) {
  return __builtin_bit_cast(float, u << 16);
}
static __device__ __forceinline__ float bfhi(unsigned int u) {
  return __builtin_bit_cast(float, u & 0xffff0000u);
}

// ------- bucket histogram over dst>>8 (LDS-aggregated, 512 buckets) -------
__global__ __launch_bounds__(256) void k_bhist(const int* __restrict__ ei,
                                               int* __restrict__ bcnt, int E) {
  __shared__ int h[512];
  const int t = threadIdx.x;
  for (int i = t; i < 512; i += 256) h[i] = 0;
  __syncthreads();
  int stride = gridDim.x * blockDim.x;
  for (int i = blockIdx.x * blockDim.x + t; i < E; i += stride)
    atomicAdd(&h[ei[E + i] >> 8], 1);
  __syncthreads();
  for (int i = t; i < 512; i += 256)
    if (h[i]) atomicAdd(&bcnt[i], h[i]);
}

// ------- one-block scan of 512 bucket counts -> bbase (513), bcur ---------
__global__ __launch_bounds__(512) void k_bscan(const int* __restrict__ bcnt,
                                               int* __restrict__ bbase,
                                               int* __restrict__ bcur, int E) {
  __shared__ int sd[512];
  const int t = threadIdx.x;
  int v = bcnt[t];
  sd[t] = v;
  __syncthreads();
#pragma unroll
  for (int off = 1; off < 512; off <<= 1) {
    int x = (t >= off) ? sd[t - off] : 0;
    __syncthreads();
    sd[t] += x;
    __syncthreads();
  }
  int ex = sd[t] - v;
  bbase[t] = ex;
  bcur[t] = ex;
  if (t == 511) bbase[512] = sd[511];  // == E
}

// ------- bucketize edges into dst>>8 regions as packed (s,d) pairs --------
__global__ __launch_bounds__(256) void k_b3(const int* __restrict__ ei,
                                            int* __restrict__ bcur,
                                            uint2* __restrict__ pairs, int E) {
  __shared__ int cntD[512];
  __shared__ int gbase[512];
  const int t = threadIdx.x;
  for (int i = t; i < 512; i += 256) cntD[i] = 0;
  __syncthreads();
  const int base = blockIdx.x * 2048;
  int s[8], d[8], rk[8];
#pragma unroll
  for (int i = 0; i < 8; ++i) {
    int e = base + i * 256 + t;
    if (e < E) {
      s[i] = ei[e];
      d[i] = ei[E + e];
      rk[i] = atomicAdd(&cntD[d[i] >> 8], 1);
    }
  }
  __syncthreads();
  for (int i = t; i < 512; i += 256)
    if (cntD[i] > 0) gbase[i] = atomicAdd(&bcur[i], cntD[i]);
  __syncthreads();
#pragma unroll
  for (int i = 0; i < 8; ++i) {
    int e = base + i * 256 + t;
    if (e < E)
      pairs[gbase[d[i] >> 8] + rk[i]] = make_uint2((unsigned)s[i], (unsigned)d[i]);
  }
}

// ------- per-bucket: count (LDS) -> scan -> row_ptr+dis -> fill col -------
__global__ __launch_bounds__(256) void k_b4x(const int* __restrict__ bbase,
                                             const uint2* __restrict__ pairs,
                                             int* __restrict__ col,
                                             int* __restrict__ row_ptr,
                                             float* __restrict__ dis, int N,
                                             int E) {
  __shared__ int cntL[256];
  __shared__ int sd[256];
  __shared__ int curL[256];
  const int n0 = blockIdx.x << 8;
  const int nn = min(256, N - n0);
  const int t = threadIdx.x;
  cntL[t] = 0;
  __syncthreads();
  const int p0 = bbase[blockIdx.x], p1 = bbase[blockIdx.x + 1];
  for (int idx = p0 + t; idx < p1; idx += 256)
    atomicAdd(&cntL[(int)pairs[idx].y - n0], 1);
  __syncthreads();
  const int c = cntL[t];
  sd[t] = c;
  __syncthreads();
#pragma unroll
  for (int off = 1; off < 256; off <<= 1) {
    int x = (t >= off) ? sd[t - off] : 0;
    __syncthreads();
    sd[t] += x;
    __syncthreads();
  }
  const int excl = sd[t] - c;
  if (t < nn) {
    row_ptr[n0 + t] = p0 + excl;
    dis[n0 + t] = 1.0f / sqrtf((float)c + 1.0f);
  }
  curL[t] = p0 + excl;
  if (blockIdx.x == gridDim.x - 1 && t == 0) row_ptr[N] = E;
  __syncthreads();
  for (int idx = p0 + t; idx < p1; idx += 256) {
    uint2 pr = pairs[idx];
    int pos = atomicAdd(&curL[(int)pr.y - n0], 1);
    col[pos] = (int)pr.x;
  }
}

// ------- graph boundaries from sorted batch -------------------------------
__global__ __launch_bounds__(256) void k_gb(const int* __restrict__ batch,
                                            int* __restrict__ gstart, int N) {
  const int i = blockIdx.x * 256 + threadIdx.x;
  if (i >= N) return;
  int b = batch[i];
  if (i == 0) {
    for (int g = 0; g <= b; ++g) gstart[g] = 0;
  } else {
    int p = batch[i - 1];
    for (int g = p + 1; g <= b; ++g) gstart[g] = i;
  }
  if (i == N - 1)
    for (int g = b + 1; g <= 8; ++g) gstart[g] = N;
}

// ---------------- pack W (KxM fp32) into B-fragment layout ----------------
static __device__ __forceinline__ void pack_one(const float* __restrict__ W,
                                                unsigned short* __restrict__ Wp,
                                                int K, int M, int t) {
  int KT = K >> 5;
  int lane = t & 63;
  int tile = t >> 6;
  int kt = tile % KT;
  int ct = tile / KT;
  int c = ct * 16 + (lane & 15);
  int k0 = kt * 32 + (lane >> 4) * 8;
  unsigned short v[8];
#pragma unroll
  for (int j = 0; j < 8; ++j) v[j] = f2bf(W[(size_t)(k0 + j) * M + c]);
  ushort4* dst = (ushort4*)&Wp[(size_t)t * 8];
  dst[0] = make_ushort4(v[0], v[1], v[2], v[3]);
  dst[1] = make_ushort4(v[4], v[5], v[6], v[7]);
}

__global__ __launch_bounds__(256) void k_packall(
    const float* __restrict__ W1, const float* __restrict__ W2,
    const float* __restrict__ W3, unsigned short* __restrict__ Wp1,
    unsigned short* __restrict__ Wp2, unsigned short* __restrict__ Wp3) {
  int t = blockIdx.x * 256 + threadIdx.x;
  if (t < 1024)
    pack_one(W1, Wp1, 128, 64, t);          // 4*4*64 frags
  else if (t < 2048)
    pack_one(W2, Wp2, 64, 128, t - 1024);   // 8*2*64
  else if (t < 6144)
    pack_one(W3, Wp3, 128, 256, t - 2048);  // 16*4*64
}

// ------- CSR agg, M=64: wave/dst; 8 sub-waves x 8 lanes x 8ch (16B loads) -
template <bool EPI>
__global__ __launch_bounds__(256) void k_agg64(const int* __restrict__ row_ptr,
                                               const int* __restrict__ col,
                                               const float* __restrict__ dis,
                                               const unsigned short* __restrict__ Hin,
                                               const float* __restrict__ bias,
                                               unsigned short* __restrict__ Pout,
                                               int N) {
  const int lane = threadIdx.x & 63;
  int d = blockIdx.x * 4 + (threadIdx.x >> 6);
  if (d >= N) return;
  const int q = lane >> 3;   // sub-wave 0..7, one edge each
  const int cl = lane & 7;   // 8 lanes x 8ch = 64 channels
  const int cb = cl * 8;
  const float disd = dis[d];
  const int beg = row_ptr[d];
  const int end = row_ptr[d + 1];
  const int deg = end - beg;
  const int nedge = min(deg, 64);

  int s_l = d;
  float w_l = 0.f;
  if (lane < nedge) {
    s_l = col[beg + lane];
    w_l = dis[s_l] * disd;
  }

  float acc[8];
#pragma unroll
  for (int k = 0; k < 8; ++k) acc[k] = 0.f;
  if (q == 0) {  // self-loop on sub-wave 0
    uint4 u = *(const uint4*)&Hin[(size_t)d * 64 + cb];
    const float sc = disd * disd;
    acc[0] = bflo(u.x) * sc; acc[1] = bfhi(u.x) * sc;
    acc[2] = bflo(u.y) * sc; acc[3] = bfhi(u.y) * sc;
    acc[4] = bflo(u.z) * sc; acc[5] = bfhi(u.z) * sc;
    acc[6] = bflo(u.w) * sc; acc[7] = bfhi(u.w) * sc;
  }

  const int padded = (nedge + 15) & ~15;
  for (int base = 0; base < padded; base += 16) {
    int e0 = base + q, e1 = base + 8 + q;
    int s0 = __shfl(s_l, e0, 64);
    float w0 = __shfl(w_l, e0, 64);
    int s1 = __shfl(s_l, e1, 64);
    float w1 = __shfl(w_l, e1, 64);
    if (e0 >= nedge) { s0 = d; w0 = 0.f; }
    if (e1 >= nedge) { s1 = d; w1 = 0.f; }
    uint4 u0 = *(const uint4*)&Hin[(size_t)s0 * 64 + cb];
    uint4 u1 = *(const uint4*)&Hin[(size_t)s1 * 64 + cb];
    acc[0] = fmaf(bflo(u0.x), w0, acc[0]); acc[1] = fmaf(bfhi(u0.x), w0, acc[1]);
    acc[2] = fmaf(bflo(u0.y), w0, acc[2]); acc[3] = fmaf(bfhi(u0.y), w0, acc[3]);
    acc[4] = fmaf(bflo(u0.z), w0, acc[4]); acc[5] = fmaf(bfhi(u0.z), w0, acc[5]);
    acc[6] = fmaf(bflo(u0.w), w0, acc[6]); acc[7] = fmaf(bfhi(u0.w), w0, acc[7]);
    acc[0] = fmaf(bflo(u1.x), w1, acc[0]); acc[1] = fmaf(bfhi(u1.x), w1, acc[1]);
    acc[2] = fmaf(bflo(u1.y), w1, acc[2]); acc[3] = fmaf(bfhi(u1.y), w1, acc[3]);
    acc[4] = fmaf(bflo(u1.z), w1, acc[4]); acc[5] = fmaf(bfhi(u1.z), w1, acc[5]);
    acc[6] = fmaf(bflo(u1.w), w1, acc[6]); acc[7] = fmaf(bfhi(u1.w), w1, acc[7]);
  }
  if (deg > 64) {
    for (int j = beg + 64 + q; j < end; j += 8) {
      int s = col[j];
      float w = dis[s] * disd;
      uint4 u = *(const uint4*)&Hin[(size_t)s * 64 + cb];
      acc[0] = fmaf(bflo(u.x), w, acc[0]); acc[1] = fmaf(bfhi(u.x), w, acc[1]);
      acc[2] = fmaf(bflo(u.y), w, acc[2]); acc[3] = fmaf(bfhi(u.y), w, acc[3]);
      acc[4] = fmaf(bflo(u.z), w, acc[4]); acc[5] = fmaf(bfhi(u.z), w, acc[5]);
      acc[6] = fmaf(bflo(u.w), w, acc[6]); acc[7] = fmaf(bfhi(u.w), w, acc[7]);
    }
  }

#pragma unroll
  for (int k = 0; k < 8; ++k) {
    acc[k] += __shfl_xor(acc[k], 8, 64);
    acc[k] += __shfl_xor(acc[k], 16, 64);
    acc[k] += __shfl_xor(acc[k], 32, 64);
  }
  if (q == 0) {
    if (EPI) {
#pragma unroll
      for (int k = 0; k < 8; ++k) acc[k] = fmaxf(acc[k] + bias[cb + k], 0.f);
    }
    uint4 o;
    o.x = (unsigned)f2bf(acc[0]) | ((unsigned)f2bf(acc[1]) << 16);
    o.y = (unsigned)f2bf(acc[2]) | ((unsigned)f2bf(acc[3]) << 16);
    o.z = (unsigned)f2bf(acc[4]) | ((unsigned)f2bf(acc[5]) << 16);
    o.w = (unsigned)f2bf(acc[6]) | ((unsigned)f2bf(acc[7]) << 16);
    *(uint4*)&Pout[(size_t)d * 64 + cb] = o;
  }
}

// ------- CSR agg, M=128: wave/dst; 4 sub-waves x 16 lanes x 8ch -----------
__global__ __launch_bounds__(256) void k_agg128(const int* __restrict__ row_ptr,
                                                const int* __restrict__ col,
                                                const float* __restrict__ dis,
                                                const unsigned short* __restrict__ Hin,
                                                unsigned short* __restrict__ Pout,
                                                int N) {
  const int lane = threadIdx.x & 63;
  int d = blockIdx.x * 4 + (threadIdx.x >> 6);
  if (d >= N) return;
  const int q = lane >> 4;    // sub-wave 0..3
  const int cl = lane & 15;   // 16 lanes x 8ch = 128 channels
  const int cb = cl * 8;
  const float disd = dis[d];
  const int beg = row_ptr[d];
  const int end = row_ptr[d + 1];
  const int deg = end - beg;
  const int nedge = min(deg, 64);

  int s_l = d;
  float w_l = 0.f;
  if (lane < nedge) {
    s_l = col[beg + lane];
    w_l = dis[s_l] * disd;
  }

  float acc[8];
#pragma unroll
  for (int k = 0; k < 8; ++k) acc[k] = 0.f;
  if (q == 0) {  // self-loop
    uint4 u = *(const uint4*)&Hin[(size_t)d * 128 + cb];
    const float sc = disd * disd;
    acc[0] = bflo(u.x) * sc; acc[1] = bfhi(u.x) * sc;
    acc[2] = bflo(u.y) * sc; acc[3] = bfhi(u.y) * sc;
    acc[4] = bflo(u.z) * sc; acc[5] = bfhi(u.z) * sc;
    acc[6] = bflo(u.w) * sc; acc[7] = bfhi(u.w) * sc;
  }

  const int padded = (nedge + 7) & ~7;
  for (int base = 0; base < padded; base += 8) {
    int e0 = base + q, e1 = base + 4 + q;
    int s0 = __shfl(s_l, e0, 64);
    float w0 = __shfl(w_l, e0, 64);
    int s1 = __shfl(s_l, e1, 64);
    float w1 = __shfl(w_l, e1, 64);
    if (e0 >= nedge) { s0 = d; w0 = 0.f; }
    if (e1 >= nedge) { s1 = d; w1 = 0.f; }
    uint4 u0 = *(const uint4*)&Hin[(size_t)s0 * 128 + cb];
    uint4 u1 = *(const uint4*)&Hin[(size_t)s1 * 128 + cb];
    acc[0] = fmaf(bflo(u0.x), w0, acc[0]); acc[1] = fmaf(bfhi(u0.x), w0, acc[1]);
    acc[2] = fmaf(bflo(u0.y), w0, acc[2]); acc[3] = fmaf(bfhi(u0.y), w0, acc[3]);
    acc[4] = fmaf(bflo(u0.z), w0, acc[4]); acc[5] = fmaf(bfhi(u0.z), w0, acc[5]);
    acc[6] = fmaf(bflo(u0.w), w0, acc[6]); acc[7] = fmaf(bfhi(u0.w), w0, acc[7]);
    acc[0] = fmaf(bflo(u1.x), w1, acc[0]); acc[1] = fmaf(bfhi(u1.x), w1, acc[1]);
    acc[2] = fmaf(bflo(u1.y), w1, acc[2]); acc[3] = fmaf(bfhi(u1.y), w1, acc[3]);
    acc[4] = fmaf(bflo(u1.z), w1, acc[4]); acc[5] = fmaf(bfhi(u1.z), w1, acc[5]);
    acc[6] = fmaf(bflo(u1.w), w1, acc[6]); acc[7] = fmaf(bfhi(u1.w), w1, acc[7]);
  }
  if (deg > 64) {
    for (int j = beg + 64 + q; j < end; j += 4) {
      int s = col[j];
      float w = dis[s] * disd;
      uint4 u = *(const uint4*)&Hin[(size_t)s * 128 + cb];
      acc[0] = fmaf(bflo(u.x), w, acc[0]); acc[1] = fmaf(bfhi(u.x), w, acc[1]);
      acc[2] = fmaf(bflo(u.y), w, acc[2]); acc[3] = fmaf(bfhi(u.y), w, acc[3]);
      acc[4] = fmaf(bflo(u.z), w, acc[4]); acc[5] = fmaf(bfhi(u.z), w, acc[5]);
      acc[6] = fmaf(bflo(u.w), w, acc[6]); acc[7] = fmaf(bfhi(u.w), w, acc[7]);
    }
  }

#pragma unroll
  for (int k = 0; k < 8; ++k) {
    acc[k] += __shfl_xor(acc[k], 16, 64);
    acc[k] += __shfl_xor(acc[k], 32, 64);
  }
  if (q == 0) {
    uint4 o;
    o.x = (unsigned)f2bf(acc[0]) | ((unsigned)f2bf(acc[1]) << 16);
    o.y = (unsigned)f2bf(acc[2]) | ((unsigned)f2bf(acc[3]) << 16);
    o.z = (unsigned)f2bf(acc[4]) | ((unsigned)f2bf(acc[5]) << 16);
    o.w = (unsigned)f2bf(acc[6]) | ((unsigned)f2bf(acc[7]) << 16);
    *(uint4*)&Pout[(size_t)d * 128 + cb] = o;
  }
}

// ------- MFMA GEMM, column-split waves: block=64 rows, wave w owns CT/4 ---
template <int K, int M, bool F32IN, bool BIAS>
__global__ __launch_bounds__(256) void k_mmx(const void* __restrict__ Ap,
                                             const unsigned short* __restrict__ Wp,
                                             const float* __restrict__ bias,
                                             unsigned short* __restrict__ Hout,
                                             int N) {
  constexpr int KT = K / 32, CTW = M / 64;  // col-tiles per wave
  __shared__ unsigned short lds[64][M + 8];  // rows 16B-aligned (M+8 even*8)
  const int lane = threadIdx.x & 63;
  const int wid = threadIdx.x >> 6;
  const int blk0 = blockIdx.x * 64;
  const int r = lane & 15;
  const int kh = lane >> 4;

  int ar[4];
#pragma unroll
  for (int rt = 0; rt < 4; ++rt) ar[rt] = min(blk0 + rt * 16 + r, N - 1);

  f32x4 acc[4][CTW];
#pragma unroll
  for (int rt = 0; rt < 4; ++rt)
#pragma unroll
    for (int c = 0; c < CTW; ++c) acc[rt][c] = (f32x4){0.f, 0.f, 0.f, 0.f};

#pragma unroll
  for (int kt = 0; kt < KT; ++kt) {
    short8v a[4];
#pragma unroll
    for (int rt = 0; rt < 4; ++rt) {
      if (F32IN) {
        const float* Af = (const float*)Ap;
        const float* p = &Af[(size_t)ar[rt] * K + kt * 32 + kh * 8];
        float4 f0 = *(const float4*)p;
        float4 f1 = *(const float4*)(p + 4);
        a[rt][0] = (short)f2bf(f0.x); a[rt][1] = (short)f2bf(f0.y);
        a[rt][2] = (short)f2bf(f0.z); a[rt][3] = (short)f2bf(f0.w);
        a[rt][4] = (short)f2bf(f1.x); a[rt][5] = (short)f2bf(f1.y);
        a[rt][6] = (short)f2bf(f1.z); a[rt][7] = (short)f2bf(f1.w);
      } else {
        const unsigned short* Ab = (const unsigned short*)Ap;
        a[rt] = *(const short8v*)&Ab[(size_t)ar[rt] * K + kt * 32 + kh * 8];
      }
    }
#pragma unroll
    for (int c = 0; c < CTW; ++c) {
      const int ct = wid * CTW + c;
      short8v b = *(const short8v*)&Wp[(size_t)((ct * KT + kt) * 64 + lane) * 8];
#pragma unroll
      for (int rt = 0; rt < 4; ++rt)
        acc[rt][c] = __builtin_amdgcn_mfma_f32_16x16x32_bf16(a[rt], b, acc[rt][c], 0, 0, 0);
    }
  }

#pragma unroll
  for (int c = 0; c < CTW; ++c) {
    const int col = (wid * CTW + c) * 16 + r;
    const float bv = BIAS ? bias[col] : 0.f;
#pragma unroll
    for (int rt = 0; rt < 4; ++rt) {
      const int lrow0 = rt * 16 + kh * 4;
#pragma unroll
      for (int reg = 0; reg < 4; ++reg) {
        float v = acc[rt][c][reg] + bv;
        if (BIAS) v = fmaxf(v, 0.f);
        lds[lrow0 + reg][col] = f2bf(v);
      }
    }
  }
  __syncthreads();
  constexpr int CBK = M / 8;          // 16B chunks per row
  constexpr int ITER = 64 * CBK / 256;
  const int t = threadIdx.x;
#pragma unroll
  for (int it = 0; it < ITER; ++it) {
    int idx = it * 256 + t;
    int row = idx / CBK;
    int cbk = idx % CBK;
    if (blk0 + row < N)
      *(uint4*)&Hout[(size_t)(blk0 + row) * M + cbk * 8] =
          *(const uint4*)&lds[row][cbk * 8];
  }
}

// ---------------- pooling: per-graph segmented sum over sorted rows -------
__global__ __launch_bounds__(256) void k_pool2(const unsigned short* __restrict__ H4,
                                               const int* __restrict__ gstart,
                                               float* __restrict__ pooled) {
  __shared__ float sd[8][256];
  const int g = blockIdx.y;
  const int s = gstart[g], e = gstart[g + 1];
  if (s >= e) return;  // uniform per block
  const int PB = gridDim.x;
  const int chunk = (e - s + PB - 1) / PB;
  const int r0 = s + blockIdx.x * chunk;
  const int r1 = min(e, r0 + chunk);

  const int t = threadIdx.x;
  const int rs = t >> 5;
  const int cl = t & 31;
  const int cb = cl * 8;

  float a[8];
#pragma unroll
  for (int k = 0; k < 8; ++k) a[k] = 0.f;

  for (int r = r0 + rs; r < r1; r += 8) {
    uint4 u = *(const uint4*)&H4[(size_t)r * 256 + cb];
    a[0] += bflo(u.x); a[1] += bfhi(u.x);
    a[2] += bflo(u.y); a[3] += bfhi(u.y);
    a[4] += bflo(u.z); a[5] += bfhi(u.z);
    a[6] += bflo(u.w); a[7] += bfhi(u.w);
  }
#pragma unroll
  for (int k = 0; k < 8; ++k) sd[rs][cb + k] = a[k];
  __syncthreads();
  float v = 0.f;
#pragma unroll
  for (int q = 0; q < 8; ++q) v += sd[q][t];
  atomicAdd(&pooled[g * 256 + t], v);
}

// ---------------- final FC: out[g] = pooled[g]/cnt . Wfc + bfc ------------
__global__ __launch_bounds__(256) void k_final(const float* __restrict__ pooled,
                                               const int* __restrict__ gstart,
                                               const float* __restrict__ Wfc,
                                               const float* __restrict__ bfc,
                                               float* __restrict__ out) {
  __shared__ float red[4];
  const int t = threadIdx.x;
  for (int g = 0; g < 8; ++g) {
    float cg = (float)(gstart[g + 1] - gstart[g]);
    float v = pooled[g * 256 + t] / cg * Wfc[t];
#pragma unroll
    for (int off = 32; off > 0; off >>= 1) v += __shfl_down(v, off, 64);
    if ((t & 63) == 0) red[t >> 6] = v;
    __syncthreads();
    if (t == 0) out[g] = red[0] + red[1] + red[2] + red[3] + bfc[0];
    __syncthreads();
  }
}

extern "C" void kernel_launch(void* const* d_in, const int* in_sizes, int n_in,
                              void* d_out, int out_size, void* d_ws,
                              size_t ws_size, hipStream_t stream) {
  const float* x = (const float*)d_in[0];
  const int* ei = (const int*)d_in[1];
  const int* batch = (const int*)d_in[2];
  const float* W1 = (const float*)d_in[3];
  const float* b1 = (const float*)d_in[4];
  const float* W2 = (const float*)d_in[5];
  const float* b2 = (const float*)d_in[6];
  const float* W3 = (const float*)d_in[7];
  const float* b3 = (const float*)d_in[8];
  const float* Wfc = (const float*)d_in[9];
  const float* bfc = (const float*)d_in[10];
  float* out = (float*)d_out;

  const int N = in_sizes[0] / 128;
  const int E = in_sizes[1] / 2;
  const int nb = (N + 255) / 256;
  const int nbk = (N + 255) >> 8;  // dst buckets (256 nodes each), <=512

  // -------- workspace layout (4-byte units) --------
  float* ws = (float*)d_ws;
  size_t o = 0;
  float* dis = ws + o;            o += (size_t)N;
  int* row_ptr = (int*)(ws + o);  o += (size_t)N + 1;
  int* bcnt = (int*)(ws + o);     o += 512;   // zeroed (with pooled)
  float* pooled = ws + o;         o += 2048;  // zeroed
  int* bbase = (int*)(ws + o);    o += 513;
  int* bcur = (int*)(ws + o);     o += 512;
  int* col = (int*)(ws + o);      o += (size_t)E;
  uint2* pairs = (uint2*)(ws + o); o += (size_t)E * 2;
  int* gstart = (int*)(ws + o);   o += 16;
  unsigned short* Wp1 = (unsigned short*)(ws + o); o += 4096;   // 128x64 bf16
  unsigned short* Wp2 = (unsigned short*)(ws + o); o += 4096;   // 64x128
  unsigned short* Wp3 = (unsigned short*)(ws + o); o += 16384;  // 128x256
  o = (o + 63) & ~(size_t)63;
  unsigned short* bufA = (unsigned short*)(ws + o); o += (size_t)N * 32;  // t1 / P2 (64ch)
  unsigned short* bufB = (unsigned short*)(ws + o); o += (size_t)N * 32;  // h2 (64ch)
  unsigned short* bufC = (unsigned short*)(ws + o); o += (size_t)N * 64;  // h3 (128ch)
  unsigned short* bufD = (unsigned short*)(ws + o); o += (size_t)N * 64;  // P3 (128ch)
  unsigned short* bufE = (unsigned short*)(ws + o); o += (size_t)N * 128; // h4 (256ch)

  // one memset covers bcnt(512) + pooled(2048), contiguous
  hipMemsetAsync(bcnt, 0, (512 + 2048) * sizeof(float), stream);

  k_bhist<<<512, 256, 0, stream>>>(ei, bcnt, E);
  k_bscan<<<1, 512, 0, stream>>>(bcnt, bbase, bcur, E);
  k_b3<<<(E + 2047) / 2048, 256, 0, stream>>>(ei, bcur, pairs, E);
  k_b4x<<<nbk, 256, 0, stream>>>(bbase, pairs, col, row_ptr, dis, N, E);
  k_gb<<<nb, 256, 0, stream>>>(batch, gstart, N);
  k_packall<<<24, 256, 0, stream>>>(W1, W2, W3, Wp1, Wp2, Wp3);

  const int ablocks = (N + 3) / 4;
  const int mblocks = (N + 63) / 64;
  // L1: t1 = x @ W1 (fp32 in, raw out); h2 = relu(agg(t1) + b1)
  k_mmx<128, 64, true, false><<<mblocks, 256, 0, stream>>>(x, Wp1, nullptr, bufA, N);
  k_agg64<true><<<ablocks, 256, 0, stream>>>(row_ptr, col, dis, bufA, b1, bufB, N);
  // L2: P2 = agg(h2); h3 = relu(P2 @ W2 + b2)
  k_agg64<false><<<ablocks, 256, 0, stream>>>(row_ptr, col, dis, bufB, nullptr, bufA, N);
  k_mmx<64, 128, false, true><<<mblocks, 256, 0, stream>>>(bufA, Wp2, b2, bufC, N);
  // L3: P3 = agg(h3); h4 = relu(P3 @ W3 + b3)
  k_agg128<<<ablocks, 256, 0, stream>>>(row_ptr, col, dis, bufC, bufD, N);
  k_mmx<128, 256, false, true><<<mblocks, 256, 0, stream>>>(bufD, Wp3, b3, bufE, N);

  k_pool2<<<dim3(128, 8), 256, 0, stream>>>(bufE, gstart, pooled);
  k_final<<<1, 256, 0, stream>>>(pooled, gstart, Wfc, bfc, out);
}